// Round 1
// baseline (1691.069 us; speedup 1.0000x reference)
//
#include <hip/hip_runtime.h>
#include <hip/hip_bf16.h>

#define N_NODES 100000
#define N_EDGES 1600000
#define H 128
#define NUM_INV 16
#define BN_EPS 1e-5f

typedef __attribute__((ext_vector_type(8))) short short8;
typedef __attribute__((ext_vector_type(4))) float f32x4;

static __device__ __forceinline__ unsigned short f2b(float x) {
    union { float f; unsigned u; } c; c.f = x;
    unsigned r = c.u + 0x7fffu + ((c.u >> 16) & 1u);
    return (unsigned short)(r >> 16);
}
static __device__ __forceinline__ float b2f(unsigned short u) {
    union { unsigned u; float f; } c; c.u = ((unsigned)u) << 16; return c.f;
}

// ---------------- K0: W1[0:256,:] -> bf16, transposed (Wt[g][f][k] = W1[g*128+k][f]) ----
__global__ void k0_wt(const float* __restrict__ W1, unsigned short* __restrict__ Wt) {
    int idx = blockIdx.x * blockDim.x + threadIdx.x;
    if (idx >= 2 * H * H) return;
    int g = idx >> 14;
    int rem = idx & 16383;
    int k = rem >> 7;      // consecutive idx -> consecutive f: coalesced reads
    int f = rem & 127;
    Wt[(size_t)g * H * H + (size_t)f * H + k] = f2b(W1[(size_t)(g * H + k) * H + f]);
}

// ---------------- K1: P = X @ W1part (+b1 for send), bf16 MFMA, M-tile 32 ---------------
__global__ __launch_bounds__(256) void k1_gemm(
    const float* __restrict__ x_send, const float* __restrict__ x_rec,
    const unsigned short* __restrict__ Wt, const float* __restrict__ b1,
    unsigned short* __restrict__ P_send, unsigned short* __restrict__ P_rec)
{
    const int g = blockIdx.y;
    const float* X = g ? x_rec : x_send;
    unsigned short* P = g ? P_rec : P_send;
    const int m0 = blockIdx.x * 32;
    const int tid = threadIdx.x;
    const int wave = tid >> 6;
    const int lane = tid & 63;
    const int quad = lane >> 4;
    const int l16 = lane & 15;
    const int n0 = wave * 32;

    const unsigned short* Wg = Wt + (size_t)g * (H * H);

    f32x4 acc[2][2];
    #pragma unroll
    for (int i = 0; i < 2; ++i)
        #pragma unroll
        for (int j = 0; j < 2; ++j)
            acc[i][j] = (f32x4){0.f, 0.f, 0.f, 0.f};

    #pragma unroll
    for (int kt = 0; kt < 4; ++kt) {
        const int kk = kt * 32;
        short8 a[2], b[2];
        #pragma unroll
        for (int ms = 0; ms < 2; ++ms) {
            const float* ap = X + (size_t)(m0 + ms * 16 + l16) * H + kk + quad * 8;
            f32x4 a0 = *(const f32x4*)ap;
            f32x4 a1 = *(const f32x4*)(ap + 4);
            short8 t;
            t[0] = (short)f2b(a0[0]); t[1] = (short)f2b(a0[1]);
            t[2] = (short)f2b(a0[2]); t[3] = (short)f2b(a0[3]);
            t[4] = (short)f2b(a1[0]); t[5] = (short)f2b(a1[1]);
            t[6] = (short)f2b(a1[2]); t[7] = (short)f2b(a1[3]);
            a[ms] = t;
        }
        #pragma unroll
        for (int ns = 0; ns < 2; ++ns)
            b[ns] = *(const short8*)(Wg + (size_t)(n0 + ns * 16 + l16) * H + kk + quad * 8);
        #pragma unroll
        for (int ms = 0; ms < 2; ++ms)
            #pragma unroll
            for (int ns = 0; ns < 2; ++ns)
                acc[ms][ns] = __builtin_amdgcn_mfma_f32_16x16x32_bf16(
                    a[ms], b[ns], acc[ms][ns], 0, 0, 0);
    }

    #pragma unroll
    for (int ms = 0; ms < 2; ++ms) {
        #pragma unroll
        for (int ns = 0; ns < 2; ++ns) {
            int col = n0 + ns * 16 + l16;
            float bias = g ? 0.f : b1[col];
            #pragma unroll
            for (int r = 0; r < 4; ++r) {
                int row = m0 + ms * 16 + quad * 4 + r;
                P[(size_t)row * H + col] = f2b(acc[ms][ns][r] + bias);
            }
        }
    }
}

// ---------------- per-edge h recompute helper (W1c in registers) ------------------------
#define LOAD_EA(ea, e, eav)                                                         \
    const f32x4* ep_ = (const f32x4*)((ea) + (size_t)(e) * NUM_INV);                \
    f32x4 e0_ = ep_[0], e1_ = ep_[1], e2_ = ep_[2], e3_ = ep_[3];                   \
    float eav[16] = {e0_[0], e0_[1], e0_[2], e0_[3], e1_[0], e1_[1], e1_[2], e1_[3],\
                     e2_[0], e2_[1], e2_[2], e2_[3], e3_[0], e3_[1], e3_[2], e3_[3]};

// ---------------- K2: batch-norm statistics (sum, sumsq per feature) --------------------
__global__ __launch_bounds__(256) void k2_stats(
    const unsigned short* __restrict__ Ps, const unsigned short* __restrict__ Pr,
    const int* __restrict__ isend, const int* __restrict__ irec,
    const float* __restrict__ ea, const float* __restrict__ W1,
    float* __restrict__ stats)
{
    const int tid = threadIdx.x;
    const int wave = tid >> 6;
    const int lane = tid & 63;
    const float* Wc = W1 + 2 * H * H;   // rows 256..271 of W1

    float wc0[NUM_INV], wc1[NUM_INV];
    #pragma unroll
    for (int k = 0; k < NUM_INV; ++k) {
        wc0[k] = Wc[k * H + lane];
        wc1[k] = Wc[k * H + 64 + lane];
    }

    float s0 = 0.f, s1 = 0.f, q0 = 0.f, q1 = 0.f;
    int wid = blockIdx.x * 4 + wave;
    int nw = gridDim.x * 4;
    for (int e = wid; e < N_EDGES; e += nw) {
        int is = isend[e], ir = irec[e];
        float h0 = b2f(Ps[(size_t)is * H + lane]) + b2f(Pr[(size_t)ir * H + lane]);
        float h1 = b2f(Ps[(size_t)is * H + 64 + lane]) + b2f(Pr[(size_t)ir * H + 64 + lane]);
        LOAD_EA(ea, e, eav)
        #pragma unroll
        for (int k = 0; k < NUM_INV; ++k) { h0 += eav[k] * wc0[k]; h1 += eav[k] * wc1[k]; }
        s0 += h0; q0 += h0 * h0; s1 += h1; q1 += h1 * h1;
    }

    __shared__ float rs[4][128];
    __shared__ float rq[4][128];
    rs[wave][lane] = s0; rs[wave][lane + 64] = s1;
    rq[wave][lane] = q0; rq[wave][lane + 64] = q1;
    __syncthreads();
    if (tid < 128) {
        float ss = rs[0][tid] + rs[1][tid] + rs[2][tid] + rs[3][tid];
        float qq = rq[0][tid] + rq[1][tid] + rq[2][tid] + rq[3][tid];
        float* st = stats + (size_t)(blockIdx.x & 63) * 256;
        atomicAdd(st + tid, ss);
        atomicAdd(st + 128 + tid, qq);
    }
}

// ---------------- K3: finalize BN -> per-feature scale/shift ----------------------------
__global__ void k3_finalize(const float* __restrict__ stats,
                            const float* __restrict__ gamma, const float* __restrict__ beta,
                            float* __restrict__ ssb)
{
    int f = threadIdx.x;
    if (f >= H) return;
    float s = 0.f, q = 0.f;
    for (int b = 0; b < 64; ++b) {
        s += stats[b * 256 + f];
        q += stats[b * 256 + 128 + f];
    }
    const float invE = 1.f / (float)N_EDGES;
    float mean = s * invE;
    float var = q * invE - mean * mean;
    float scale = gamma[f] * rsqrtf(var + BN_EPS);
    ssb[f] = scale;
    ssb[H + f] = beta[f] - mean * scale;
}

// ---------------- K4: recompute h, affine+SiLU, gate, weighted scatter-add --------------
__global__ __launch_bounds__(256) void k4_scatter(
    const unsigned short* __restrict__ Ps, const unsigned short* __restrict__ Pr,
    const int* __restrict__ isend, const int* __restrict__ irec,
    const float* __restrict__ ea, const float* __restrict__ W1,
    const float* __restrict__ ssb, const float* __restrict__ Winf,
    const float* __restrict__ binf_p, float* __restrict__ out)
{
    const int tid = threadIdx.x;
    const int wave = tid >> 6;
    const int lane = tid & 63;
    const float* Wc = W1 + 2 * H * H;

    float wc0[NUM_INV], wc1[NUM_INV];
    #pragma unroll
    for (int k = 0; k < NUM_INV; ++k) {
        wc0[k] = Wc[k * H + lane];
        wc1[k] = Wc[k * H + 64 + lane];
    }
    float sc0 = ssb[lane], sc1 = ssb[64 + lane];
    float sh0 = ssb[128 + lane], sh1 = ssb[192 + lane];
    float wi0 = Winf[lane], wi1 = Winf[64 + lane];
    float binf = binf_p[0];

    int wid = blockIdx.x * 4 + wave;
    int nw = gridDim.x * 4;
    for (int e = wid; e < N_EDGES; e += nw) {
        int is = isend[e], ir = irec[e];
        float h0 = b2f(Ps[(size_t)is * H + lane]) + b2f(Pr[(size_t)ir * H + lane]);
        float h1 = b2f(Ps[(size_t)is * H + 64 + lane]) + b2f(Pr[(size_t)ir * H + 64 + lane]);
        LOAD_EA(ea, e, eav)
        #pragma unroll
        for (int k = 0; k < NUM_INV; ++k) { h0 += eav[k] * wc0[k]; h1 += eav[k] * wc1[k]; }
        h0 = h0 * sc0 + sh0;
        h1 = h1 * sc1 + sh1;
        float m0 = h0 / (1.f + __expf(-h0));   // SiLU
        float m1 = h1 / (1.f + __expf(-h1));
        float p = m0 * wi0 + m1 * wi1;
        #pragma unroll
        for (int off = 32; off; off >>= 1) p += __shfl_xor(p, off, 64);
        float ew = 1.f / (1.f + __expf(-(p + binf)));
        float* op = out + (size_t)ir * H;
        atomicAdd(op + lane, m0 * ew);
        atomicAdd(op + 64 + lane, m1 * ew);
    }
}

// ---------------- launcher --------------------------------------------------------------
extern "C" void kernel_launch(void* const* d_in, const int* in_sizes, int n_in,
                              void* d_out, int out_size, void* d_ws, size_t ws_size,
                              hipStream_t stream)
{
    const float* x_send = (const float*)d_in[0];
    const float* x_rec  = (const float*)d_in[1];
    const int*   isend  = (const int*)d_in[2];
    const int*   irec   = (const int*)d_in[3];
    const float* ea     = (const float*)d_in[4];
    const float* W1     = (const float*)d_in[5];
    const float* b1     = (const float*)d_in[6];
    const float* gamma  = (const float*)d_in[7];
    const float* beta   = (const float*)d_in[8];
    const float* Winf   = (const float*)d_in[9];
    const float* binf   = (const float*)d_in[10];
    float* out = (float*)d_out;

    char* ws = (char*)d_ws;
    unsigned short* Ps = (unsigned short*)(ws);                 // 25,600,000 B
    unsigned short* Pr = (unsigned short*)(ws + 25600000);      // 25,600,000 B
    unsigned short* Wt = (unsigned short*)(ws + 51200000);      // 65,536 B
    float* stats       = (float*)(ws + 51265536);               // 65,536 B
    float* ssb         = (float*)(ws + 51331072);               // 1,024 B

    hipMemsetAsync(stats, 0, 64 * 256 * sizeof(float), stream);
    hipMemsetAsync(out, 0, (size_t)out_size * sizeof(float), stream);

    k0_wt<<<(2 * H * H + 255) / 256, 256, 0, stream>>>(W1, Wt);
    dim3 g1(3125, 2, 1);   // 100000 / 32 = 3125 exactly
    k1_gemm<<<g1, 256, 0, stream>>>(x_send, x_rec, Wt, b1, Ps, Pr);
    k2_stats<<<2048, 256, 0, stream>>>(Ps, Pr, isend, irec, ea, W1, stats);
    k3_finalize<<<1, 128, 0, stream>>>(stats, gamma, beta, ssb);
    k4_scatter<<<2048, 256, 0, stream>>>(Ps, Pr, isend, irec, ea, W1, ssb, Winf, binf, out);
}

// Round 2
// 1053.481 us; speedup vs baseline: 1.6052x; 1.6052x over previous
//
#include <hip/hip_runtime.h>
#include <hip/hip_bf16.h>

#define N_NODES 100000
#define N_EDGES 1600000
#define H 128
#define NUM_INV 16
#define BN_EPS 1e-5f

typedef __attribute__((ext_vector_type(8))) short short8;
typedef __attribute__((ext_vector_type(4))) float f32x4;

static __device__ __forceinline__ unsigned short f2b(float x) {
    union { float f; unsigned u; } c; c.f = x;
    unsigned r = c.u + 0x7fffu + ((c.u >> 16) & 1u);
    return (unsigned short)(r >> 16);
}
static __device__ __forceinline__ float b2f(unsigned short u) {
    union { unsigned u; float f; } c; c.u = ((unsigned)u) << 16; return c.f;
}

// ---------------- K0: W1[0:256,:] -> bf16, transposed ----------------------------------
__global__ void k0_wt(const float* __restrict__ W1, unsigned short* __restrict__ Wt) {
    int idx = blockIdx.x * blockDim.x + threadIdx.x;
    if (idx >= 2 * H * H) return;
    int g = idx >> 14;
    int rem = idx & 16383;
    int k = rem >> 7;
    int f = rem & 127;
    Wt[(size_t)g * H * H + (size_t)f * H + k] = f2b(W1[(size_t)(g * H + k) * H + f]);
}

// ---------------- K1: P = X @ W1part (+b1 for send), bf16 MFMA, M-tile 32 ---------------
__global__ __launch_bounds__(256) void k1_gemm(
    const float* __restrict__ x_send, const float* __restrict__ x_rec,
    const unsigned short* __restrict__ Wt, const float* __restrict__ b1,
    unsigned short* __restrict__ P_send, unsigned short* __restrict__ P_rec)
{
    const int g = blockIdx.y;
    const float* X = g ? x_rec : x_send;
    unsigned short* P = g ? P_rec : P_send;
    const int m0 = blockIdx.x * 32;
    const int tid = threadIdx.x;
    const int wave = tid >> 6;
    const int lane = tid & 63;
    const int quad = lane >> 4;
    const int l16 = lane & 15;
    const int n0 = wave * 32;

    const unsigned short* Wg = Wt + (size_t)g * (H * H);

    f32x4 acc[2][2];
    #pragma unroll
    for (int i = 0; i < 2; ++i)
        #pragma unroll
        for (int j = 0; j < 2; ++j)
            acc[i][j] = (f32x4){0.f, 0.f, 0.f, 0.f};

    #pragma unroll
    for (int kt = 0; kt < 4; ++kt) {
        const int kk = kt * 32;
        short8 a[2], b[2];
        #pragma unroll
        for (int ms = 0; ms < 2; ++ms) {
            const float* ap = X + (size_t)(m0 + ms * 16 + l16) * H + kk + quad * 8;
            f32x4 a0 = *(const f32x4*)ap;
            f32x4 a1 = *(const f32x4*)(ap + 4);
            short8 t;
            t[0] = (short)f2b(a0[0]); t[1] = (short)f2b(a0[1]);
            t[2] = (short)f2b(a0[2]); t[3] = (short)f2b(a0[3]);
            t[4] = (short)f2b(a1[0]); t[5] = (short)f2b(a1[1]);
            t[6] = (short)f2b(a1[2]); t[7] = (short)f2b(a1[3]);
            a[ms] = t;
        }
        #pragma unroll
        for (int ns = 0; ns < 2; ++ns)
            b[ns] = *(const short8*)(Wg + (size_t)(n0 + ns * 16 + l16) * H + kk + quad * 8);
        #pragma unroll
        for (int ms = 0; ms < 2; ++ms)
            #pragma unroll
            for (int ns = 0; ns < 2; ++ns)
                acc[ms][ns] = __builtin_amdgcn_mfma_f32_16x16x32_bf16(
                    a[ms], b[ns], acc[ms][ns], 0, 0, 0);
    }

    #pragma unroll
    for (int ms = 0; ms < 2; ++ms) {
        #pragma unroll
        for (int ns = 0; ns < 2; ++ns) {
            int col = n0 + ns * 16 + l16;
            float bias = g ? 0.f : b1[col];
            #pragma unroll
            for (int r = 0; r < 4; ++r) {
                int row = m0 + ms * 16 + quad * 4 + r;
                P[(size_t)row * H + col] = f2b(acc[ms][ns][r] + bias);
            }
        }
    }
}

// ---------------- CSR build ------------------------------------------------------------
__global__ void k_deg(const int* __restrict__ irec, int* __restrict__ deg) {
    int e = blockIdx.x * 256 + threadIdx.x;
    if (e < N_EDGES) atomicAdd(&deg[irec[e]], 1);
}

__global__ __launch_bounds__(512) void k_scanA(const int* __restrict__ deg, int* __restrict__ bsum) {
    __shared__ int sh[512];
    int t = threadIdx.x;
    int n = blockIdx.x * 512 + t;
    int v = (n < N_NODES) ? deg[n] : 0;
    sh[t] = v; __syncthreads();
    for (int d = 1; d < 512; d <<= 1) {
        int x = (t >= d) ? sh[t - d] : 0;
        __syncthreads();
        sh[t] += x;
        __syncthreads();
    }
    if (t == 511) bsum[blockIdx.x] = sh[511];
}

__global__ __launch_bounds__(256) void k_scanB(const int* __restrict__ bsum, int* __restrict__ bbase) {
    __shared__ int sh[256];
    int t = threadIdx.x;
    int v = (t < 196) ? bsum[t] : 0;
    sh[t] = v; __syncthreads();
    for (int d = 1; d < 256; d <<= 1) {
        int x = (t >= d) ? sh[t - d] : 0;
        __syncthreads();
        sh[t] += x;
        __syncthreads();
    }
    if (t < 196) bbase[t] = sh[t] - v;   // exclusive
}

__global__ __launch_bounds__(512) void k_scanC(const int* __restrict__ deg, const int* __restrict__ bbase,
                                               int* __restrict__ off, int* __restrict__ cursor) {
    __shared__ int sh[512];
    int t = threadIdx.x;
    int n = blockIdx.x * 512 + t;
    int v = (n < N_NODES) ? deg[n] : 0;
    sh[t] = v; __syncthreads();
    for (int d = 1; d < 512; d <<= 1) {
        int x = (t >= d) ? sh[t - d] : 0;
        __syncthreads();
        sh[t] += x;
        __syncthreads();
    }
    if (n < N_NODES) {
        int o = bbase[blockIdx.x] + sh[t] - v;   // exclusive prefix
        off[n] = o;
        cursor[n] = o;
    }
}

__global__ void k_perm(const int* __restrict__ irec, int* __restrict__ cursor,
                       int* __restrict__ pos, int* __restrict__ perm) {
    int e = blockIdx.x * 256 + threadIdx.x;
    if (e >= N_EDGES) return;
    int p = atomicAdd(&cursor[irec[e]], 1);
    pos[e] = p;
    perm[p] = e;
}

// ---------------- K2: BN stats (+ optional bf16 h store into CSR slots) -----------------
__global__ __launch_bounds__(256) void k2_stats(
    const unsigned short* __restrict__ Ps, const unsigned short* __restrict__ Pr,
    const int* __restrict__ isend, const int* __restrict__ irec,
    const float* __restrict__ ea, const float* __restrict__ W1,
    const int* __restrict__ pos, unsigned short* __restrict__ hc,
    float* __restrict__ stats)
{
    const int tid = threadIdx.x;
    const int wave = tid >> 6;
    const int lane = tid & 63;
    const int f0 = lane * 2;
    const float* Wc = W1 + 2 * H * H;

    float wca[NUM_INV], wcb[NUM_INV];
    #pragma unroll
    for (int k = 0; k < NUM_INV; ++k) {
        wca[k] = Wc[k * H + f0];
        wcb[k] = Wc[k * H + f0 + 1];
    }

    float s0 = 0.f, s1 = 0.f, q0 = 0.f, q1 = 0.f;
    int wid = blockIdx.x * 4 + wave;
    int nw = gridDim.x * 4;
    for (int e = wid; e < N_EDGES; e += nw) {
        int eu = __builtin_amdgcn_readfirstlane(e);
        int is = isend[eu], ir = irec[eu];
        unsigned ua = *(const unsigned*)(Ps + (size_t)is * H + f0);
        unsigned ub = *(const unsigned*)(Pr + (size_t)ir * H + f0);
        float h0 = b2f((unsigned short)ua) + b2f((unsigned short)ub);
        float h1 = b2f((unsigned short)(ua >> 16)) + b2f((unsigned short)(ub >> 16));
        const f32x4* ep = (const f32x4*)(ea + (size_t)eu * NUM_INV);
        f32x4 e0 = ep[0], e1 = ep[1], e2 = ep[2], e3 = ep[3];
        float ev[16] = {e0[0],e0[1],e0[2],e0[3], e1[0],e1[1],e1[2],e1[3],
                        e2[0],e2[1],e2[2],e2[3], e3[0],e3[1],e3[2],e3[3]};
        #pragma unroll
        for (int k = 0; k < NUM_INV; ++k) { h0 += ev[k] * wca[k]; h1 += ev[k] * wcb[k]; }
        if (hc) {
            int p = pos[eu];
            unsigned up = ((unsigned)f2b(h1) << 16) | (unsigned)f2b(h0);
            *(unsigned*)(hc + (size_t)p * H + f0) = up;
        }
        s0 += h0; q0 += h0 * h0; s1 += h1; q1 += h1 * h1;
    }

    __shared__ float rs[4][128];
    __shared__ float rq[4][128];
    rs[wave][f0] = s0; rs[wave][f0 + 1] = s1;
    rq[wave][f0] = q0; rq[wave][f0 + 1] = q1;
    __syncthreads();
    if (tid < 128) {
        float ss = rs[0][tid] + rs[1][tid] + rs[2][tid] + rs[3][tid];
        float qq = rq[0][tid] + rq[1][tid] + rq[2][tid] + rq[3][tid];
        float* st = stats + (size_t)(blockIdx.x & 63) * 256;
        atomicAdd(st + tid, ss);
        atomicAdd(st + 128 + tid, qq);
    }
}

// ---------------- K3: finalize BN -> per-feature scale/shift ----------------------------
__global__ void k3_finalize(const float* __restrict__ stats,
                            const float* __restrict__ gamma, const float* __restrict__ beta,
                            float* __restrict__ ssb)
{
    int f = threadIdx.x;
    if (f >= H) return;
    float s = 0.f, q = 0.f;
    for (int b = 0; b < 64; ++b) {
        s += stats[b * 256 + f];
        q += stats[b * 256 + 128 + f];
    }
    const float invE = 1.f / (float)N_EDGES;
    float mean = s * invE;
    float var = q * invE - mean * mean;
    float scale = gamma[f] * rsqrtf(var + BN_EPS);
    ssb[f] = scale;
    ssb[H + f] = beta[f] - mean * scale;
}

// ---------------- K4a: h-materialized pass 2 — streaming, atomic-free -------------------
__global__ __launch_bounds__(256) void k4_hmat(
    const unsigned short* __restrict__ hc, const int* __restrict__ off,
    const int* __restrict__ deg, const float* __restrict__ ssb,
    const float* __restrict__ Winf, const float* __restrict__ binf_p,
    float* __restrict__ out)
{
    const int tid = threadIdx.x;
    const int wave = tid >> 6;
    const int lane = tid & 63;
    const int f0 = lane * 2;
    int n = blockIdx.x * 4 + wave;
    int nu = __builtin_amdgcn_readfirstlane(n);
    int start = off[nu];
    int d = deg[nu];

    float sc0 = ssb[f0], sc1 = ssb[f0 + 1];
    float sh0 = ssb[H + f0], sh1 = ssb[H + f0 + 1];
    float wi0 = Winf[f0], wi1 = Winf[f0 + 1];
    float bi = binf_p[0];

    float a0 = 0.f, a1 = 0.f;
    const unsigned short* hp = hc + (size_t)start * H;
    for (int i = 0; i < d; ++i, hp += H) {
        unsigned u = *(const unsigned*)(hp + f0);
        float h0 = b2f((unsigned short)u) * sc0 + sh0;
        float h1 = b2f((unsigned short)(u >> 16)) * sc1 + sh1;
        float m0 = h0 / (1.f + __expf(-h0));
        float m1 = h1 / (1.f + __expf(-h1));
        float p = m0 * wi0 + m1 * wi1;
        #pragma unroll
        for (int o = 32; o; o >>= 1) p += __shfl_xor(p, o, 64);
        float ew = 1.f / (1.f + __expf(-(p + bi)));
        a0 += m0 * ew; a1 += m1 * ew;
    }
    *(float2*)(out + (size_t)nu * H + f0) = make_float2(a0, a1);
}

// ---------------- K4b: fallback — CSR re-gather pass 2, atomic-free ---------------------
__global__ __launch_bounds__(256) void k4_csr(
    const unsigned short* __restrict__ Ps, const unsigned short* __restrict__ Pr,
    const int* __restrict__ isend, const float* __restrict__ ea,
    const float* __restrict__ W1, const int* __restrict__ off,
    const int* __restrict__ deg, const int* __restrict__ perm,
    const float* __restrict__ ssb, const float* __restrict__ Winf,
    const float* __restrict__ binf_p, float* __restrict__ out)
{
    const int tid = threadIdx.x;
    const int wave = tid >> 6;
    const int lane = tid & 63;
    const int f0 = lane * 2;
    const float* Wc = W1 + 2 * H * H;

    float wca[NUM_INV], wcb[NUM_INV];
    #pragma unroll
    for (int k = 0; k < NUM_INV; ++k) {
        wca[k] = Wc[k * H + f0];
        wcb[k] = Wc[k * H + f0 + 1];
    }

    int n = blockIdx.x * 4 + wave;
    int nu = __builtin_amdgcn_readfirstlane(n);
    int start = off[nu];
    int d = deg[nu];

    unsigned ub = *(const unsigned*)(Pr + (size_t)nu * H + f0);
    float pr0 = b2f((unsigned short)ub);
    float pr1 = b2f((unsigned short)(ub >> 16));

    float sc0 = ssb[f0], sc1 = ssb[f0 + 1];
    float sh0 = ssb[H + f0], sh1 = ssb[H + f0 + 1];
    float wi0 = Winf[f0], wi1 = Winf[f0 + 1];
    float bi = binf_p[0];

    float a0 = 0.f, a1 = 0.f;
    for (int i = 0; i < d; ++i) {
        int e = __builtin_amdgcn_readfirstlane(perm[start + i]);
        int is = isend[e];
        unsigned ua = *(const unsigned*)(Ps + (size_t)is * H + f0);
        float h0 = pr0 + b2f((unsigned short)ua);
        float h1 = pr1 + b2f((unsigned short)(ua >> 16));
        const f32x4* ep = (const f32x4*)(ea + (size_t)e * NUM_INV);
        f32x4 e0 = ep[0], e1 = ep[1], e2 = ep[2], e3 = ep[3];
        float ev[16] = {e0[0],e0[1],e0[2],e0[3], e1[0],e1[1],e1[2],e1[3],
                        e2[0],e2[1],e2[2],e2[3], e3[0],e3[1],e3[2],e3[3]};
        #pragma unroll
        for (int k = 0; k < NUM_INV; ++k) { h0 += ev[k] * wca[k]; h1 += ev[k] * wcb[k]; }
        h0 = h0 * sc0 + sh0;
        h1 = h1 * sc1 + sh1;
        float m0 = h0 / (1.f + __expf(-h0));
        float m1 = h1 / (1.f + __expf(-h1));
        float p = m0 * wi0 + m1 * wi1;
        #pragma unroll
        for (int o = 32; o; o >>= 1) p += __shfl_xor(p, o, 64);
        float ew = 1.f / (1.f + __expf(-(p + bi)));
        a0 += m0 * ew; a1 += m1 * ew;
    }
    *(float2*)(out + (size_t)nu * H + f0) = make_float2(a0, a1);
}

// ---------------- launcher --------------------------------------------------------------
extern "C" void kernel_launch(void* const* d_in, const int* in_sizes, int n_in,
                              void* d_out, int out_size, void* d_ws, size_t ws_size,
                              hipStream_t stream)
{
    const float* x_send = (const float*)d_in[0];
    const float* x_rec  = (const float*)d_in[1];
    const int*   isend  = (const int*)d_in[2];
    const int*   irec   = (const int*)d_in[3];
    const float* ea     = (const float*)d_in[4];
    const float* W1     = (const float*)d_in[5];
    const float* b1     = (const float*)d_in[6];
    const float* gamma  = (const float*)d_in[7];
    const float* beta   = (const float*)d_in[8];
    const float* Winf   = (const float*)d_in[9];
    const float* binf   = (const float*)d_in[10];
    float* out = (float*)d_out;

    char* ws = (char*)d_ws;
    unsigned short* Ps = (unsigned short*)(ws);                     // 25,600,000
    unsigned short* Pr = (unsigned short*)(ws + 25600000);          // 25,600,000
    unsigned short* Wt = (unsigned short*)(ws + 51200000);          // 65,536
    float* stats       = (float*)(ws + 51265536);                   // 65,536
    float* ssb         = (float*)(ws + 51331072);                   // 1,024
    int* deg           = (int*)(ws + 51332096);                     // 400,000
    int* off           = (int*)(ws + 51732096);                     // 400,000
    int* cursor        = (int*)(ws + 52132096);                     // 400,000
    int* bsum          = (int*)(ws + 52532096);                     // 1,024
    int* bbase         = (int*)(ws + 52533120);                     // 1,024
    int* pos           = (int*)(ws + 52534144);                     // 6,400,000
    int* perm          = (int*)(ws + 58934144);                     // 6,400,000 -> 65,334,144
    unsigned short* hc = (unsigned short*)(ws + 65536000);          // 409,600,000

    const bool hmat = ws_size >= (size_t)65536000 + (size_t)409600000;

    hipMemsetAsync(stats, 0, 64 * 256 * sizeof(float), stream);
    hipMemsetAsync(deg, 0, N_NODES * sizeof(int), stream);

    k0_wt<<<(2 * H * H + 255) / 256, 256, 0, stream>>>(W1, Wt);
    dim3 g1(3125, 2, 1);
    k1_gemm<<<g1, 256, 0, stream>>>(x_send, x_rec, Wt, b1, Ps, Pr);

    k_deg<<<N_EDGES / 256, 256, 0, stream>>>(irec, deg);
    k_scanA<<<196, 512, 0, stream>>>(deg, bsum);
    k_scanB<<<1, 256, 0, stream>>>(bsum, bbase);
    k_scanC<<<196, 512, 0, stream>>>(deg, bbase, off, cursor);
    k_perm<<<N_EDGES / 256, 256, 0, stream>>>(irec, cursor, pos, perm);

    k2_stats<<<2048, 256, 0, stream>>>(Ps, Pr, isend, irec, ea, W1,
                                       pos, hmat ? hc : (unsigned short*)nullptr, stats);
    k3_finalize<<<1, 128, 0, stream>>>(stats, gamma, beta, ssb);

    if (hmat) {
        k4_hmat<<<N_NODES / 4, 256, 0, stream>>>(hc, off, deg, ssb, Winf, binf, out);
    } else {
        k4_csr<<<N_NODES / 4, 256, 0, stream>>>(Ps, Pr, isend, ea, W1, off, deg, perm,
                                                ssb, Winf, binf, out);
    }
}